// Round 22
// baseline (311.447 us; speedup 1.0000x reference)
//
#include <hip/hip_runtime.h>
#include <stdint.h>

// B=4, S=2048, H=16, Dh=64, model dim 1024. K,V inputs ignored (reference
// attends Q against itself).
#define S_LEN 2048
#define DH    64
#define NH    16
#define DM    1024
#define NBH   64
#define NT    (S_LEN / 64)

typedef float    f32x16 __attribute__((ext_vector_type(16)));
typedef float    f32x4  __attribute__((ext_vector_type(4)));
typedef _Float16 half8  __attribute__((ext_vector_type(8)));
typedef _Float16 half4  __attribute__((ext_vector_type(4)));
typedef _Float16 half2v __attribute__((ext_vector_type(2)));

// ---------- attention v11: v10 compute, re-partitioned for concurrency ----------
// R19 post-mortem: v10 (P-in-registers) = 115.3us ~= v6 115.7 (null): LDS volume
// -29% but SQ_LDS_BANK_CONFLICT 6.29M->10.49M (+67%, new l31 frag-read pattern)
// cancelled it. Counters: Mfma 26 / VALU 47 / HBM 6 / Occ 37 -- NO pipe >50% ->
// concurrency-limited: grid 1024 WGs = 4 WGs/CU, 4 big 4-wave barrier groups;
// each __syncthreads idles 25% of the CU.
// v11: identical per-wave compute; WG = 2 waves (128 thr) covering 64 q; grid
// 2048 WGs = 8 WGs/CU = 8 independent 2-wave barrier groups (stalls decorrelate,
// barriers resolve faster). LDS 8x16KB=128<=160 ✓. Staging re-split for 128 thr:
//  Pass A: rA=tid>>1, c4=2*cl+(tid&1) (cl=0,1) -- even/odd lanes take different
//    dword pairs so per-instr writes stay 4-access/bank (naive {2cl,2cl+1} split
//    would be 8/bank). 8 float4 loads, 8 half4 writes.
//  Pass B: kj0=(tid&15)*4, d0b=(tid>>4)*8, 8 d-rows: 8 float4 loads (4 rows x
//    32B), 8 half4 transposed writes; per-instr rows share r&7=dd, chunks cover
//    0..7 x8 lanes, offsets split by kj0&7 in {0,4} -> 4-access/bank ✓.
// Cost: each tile staged by 2x WGs -> FETCH ~2x (~36MB, L2-absorbed; NOT spill).
// Compute (validated v10): 32x32 MFMA, P in regs via cvt_pkrtz+permlane32_swap.
// LDS element (row,c) at row*64 + ((c>>3) ^ (row&7))*8 + (c&7).
// XCD swizzle: 2048 WGs, %8==0 -> bijective logical=(bid&7)*256+(bid>>3).
__global__ void attn_v11_kernel(const float* __restrict__ Q,
                                float* __restrict__ out) {
    __shared__ __align__(16) _Float16 KnS[64 * 64];      // [kj][d]  8 KB
    __shared__ __align__(16) _Float16 KtS[64 * 64];      // [d][kj]  8 KB

    const int tid  = threadIdx.x;
    const int w    = tid >> 6;             // 0..1
    const int lane = tid & 63;
    const int l31  = lane & 31;
    const int hi   = lane >> 5;

    const int bid     = blockIdx.x;
    const int logical = (bid & 7) * 256 + (bid >> 3);   // bijective: 2048 % 8 == 0
    const int qblk    = logical & 31;      // 32 WGs per bh (64 q each)
    const int bh      = logical >> 5;
    const int b = bh >> 4, h = bh & 15;
    const int q0      = qblk * 64 + w * 32;   // 32 q per wave

    const float* qbase = Q + (size_t)b * S_LEN * DM + h * DH;   // + s*DM + d

    // Q fragments (B-operand of S^T): lane holds Q[q=q0+l31][d = s*16 + hi*8 + j]
    half8 qreg[4];
    #pragma unroll
    for (int s = 0; s < 4; ++s) {
        const float* p = qbase + (size_t)(q0 + l31) * DM + s * 16 + hi * 8;
        const float4 f0 = *(const float4*)p;
        const float4 f1 = *(const float4*)(p + 4);
        qreg[s] = (half8){ (_Float16)f0.x, (_Float16)f0.y, (_Float16)f0.z, (_Float16)f0.w,
                           (_Float16)f1.x, (_Float16)f1.y, (_Float16)f1.z, (_Float16)f1.w };
    }

    // fixed per-row m = qs*||q||^2 (validated R1/R2). lane's d-subset + partner's.
    const float qs = 0.18033688011112042f;   // log2(e)/sqrt(64)
    float part = 0.f;
    #pragma unroll
    for (int s = 0; s < 4; ++s)
        #pragma unroll
        for (int j = 0; j < 8; ++j) { const float x = (float)qreg[s][j]; part += x * x; }
    part += __shfl_xor(part, 32, 64);
    const float m_c = qs * part;             // for row q = q0 + l31

    // ---- staging pass A (KnS): rA = tid>>1; c4 = 2*cl + (tid&1), cl=0,1 ----
    const int rA = tid >> 1;               // 0..63
    const int t1 = tid & 1;
    const float* srcA = qbase + (size_t)rA * DM;                 // + tt*64*DM
    _Float16* knA[8];                       // [cl*4 + j]
    int   aoff[8];
    #pragma unroll
    for (int cl = 0; cl < 2; ++cl)
        #pragma unroll
        for (int j = 0; j < 4; ++j) {
            const int c4 = 2 * cl + t1;
            const int chunk = cl + 2 * j;                        // d>>3 for d=c4*4+j*16
            knA[cl * 4 + j] = &KnS[rA * 64 + ((chunk ^ (rA & 7)) * 8) + t1 * 4];
            aoff[cl * 4 + j] = c4 * 4 + j * 16;
        }
    // ---- staging pass B (KtS): kj0=(tid&15)*4, d0b=(tid>>4)*8, 8 d-rows ----
    const int kj0 = (tid & 15) * 4;        // 0..60
    const int d0b = (tid >> 4) * 8;        // 0..56
    const float* srcB = qbase + (size_t)kj0 * DM + d0b;          // + tt*64*DM + i*DM
    _Float16* ktB[8];
    #pragma unroll
    for (int dd = 0; dd < 8; ++dd) {
        const int dr = d0b + dd;                                  // dr&7 == dd
        ktB[dd] = &KtS[dr * 64 + (((kj0 >> 3) ^ dd) * 8) + (kj0 & 7)];
    }

    f32x16 O0 = { 0.f,0.f,0.f,0.f, 0.f,0.f,0.f,0.f, 0.f,0.f,0.f,0.f, 0.f,0.f,0.f,0.f };
    f32x16 O1 = { 0.f,0.f,0.f,0.f, 0.f,0.f,0.f,0.f, 0.f,0.f,0.f,0.f, 0.f,0.f,0.f,0.f };
    float lsum = 0.f;

    for (int tt = 0; tt < NT; ++tt) {
        __syncthreads();                         // prior tile's LDS reads done

        // ---- fused staging: fp32 tile -> f16 KnS + KtS (bank-balanced) ----
        float4 av[8];
        #pragma unroll
        for (int i = 0; i < 8; ++i)
            av[i] = *(const float4*)(srcA + (size_t)(tt * 64) * DM + aoff[i]);
        float4 bvA[4], bvB[4];
        #pragma unroll
        for (int i = 0; i < 4; ++i) {
            const float* pb = srcB + (size_t)(tt * 64 + i) * DM;
            bvA[i] = *(const float4*)pb;
            bvB[i] = *(const float4*)(pb + 4);
        }

        #pragma unroll
        for (int i = 0; i < 8; ++i) {
            const half4 ha = (half4){ (_Float16)av[i].x, (_Float16)av[i].y,
                                      (_Float16)av[i].z, (_Float16)av[i].w };
            *(half4*)knA[i] = ha;                // row rA
        }
        #pragma unroll
        for (int dd = 0; dd < 8; ++dd) {
            half4 tv;
            #pragma unroll
            for (int i = 0; i < 4; ++i)
                tv[i] = (dd < 4) ? (_Float16)bvA[i][dd] : (_Float16)bvB[i][dd - 4];
            *(half4*)ktB[dd] = tv;               // row d0b+dd, kj = kj0..kj0+3
        }
        __syncthreads();                         // tile visible to both waves

        // ---- per kj-tile (kt): S^T (4 chained MFMAs) -> exp -> pack/swap -> PV ----
        #pragma unroll
        for (int kt = 0; kt < 2; ++kt) {
            f32x16 acc = { 0.f,0.f,0.f,0.f, 0.f,0.f,0.f,0.f,
                           0.f,0.f,0.f,0.f, 0.f,0.f,0.f,0.f };
            #pragma unroll
            for (int s = 0; s < 4; ++s) {
                const half8 a = *(const half8*)&KnS[(kt * 32 + l31) * 64 +
                                                    (((2 * s + hi) ^ (l31 & 7)) * 8)];
                acc = __builtin_amdgcn_mfma_f32_32x32x16_f16(a, qreg[s], acc, 0, 0, 0);
            }
            // p[r] = exp2(qs*S - m) for kj=(r&3)+8*(r>>2)+4*hi+32*kt, q=l31
            float p[16];
            #pragma unroll
            for (int r = 0; r < 16; ++r) {
                p[r] = __builtin_amdgcn_exp2f(__builtin_fmaf(acc[r], qs, -m_c));
                lsum += p[r];
            }
            // pack pairs -> dwords (kj ascending within each 4-block)
            half2v d0 = __builtin_bit_cast(half2v, __builtin_amdgcn_cvt_pkrtz(p[0],  p[1]));   // kj 0,1 (+4hi)
            half2v d1 = __builtin_bit_cast(half2v, __builtin_amdgcn_cvt_pkrtz(p[2],  p[3]));   // kj 2,3
            half2v d2 = __builtin_bit_cast(half2v, __builtin_amdgcn_cvt_pkrtz(p[4],  p[5]));   // kj 8,9
            half2v d3 = __builtin_bit_cast(half2v, __builtin_amdgcn_cvt_pkrtz(p[6],  p[7]));   // kj 10,11
            half2v d4 = __builtin_bit_cast(half2v, __builtin_amdgcn_cvt_pkrtz(p[8],  p[9]));   // kj 16,17
            half2v d5 = __builtin_bit_cast(half2v, __builtin_amdgcn_cvt_pkrtz(p[10], p[11]));  // kj 18,19
            half2v d6 = __builtin_bit_cast(half2v, __builtin_amdgcn_cvt_pkrtz(p[12], p[13]));  // kj 24,25
            half2v d7 = __builtin_bit_cast(half2v, __builtin_amdgcn_cvt_pkrtz(p[14], p[15]));  // kj 26,27
            // half-exchange: v_permlane32_swap: a.hi32lanes <-> b.lo32lanes.
            asm volatile("v_permlane32_swap_b32 %0, %1" : "+v"(d0), "+v"(d2));
            asm volatile("v_permlane32_swap_b32 %0, %1" : "+v"(d1), "+v"(d3));
            asm volatile("v_permlane32_swap_b32 %0, %1" : "+v"(d4), "+v"(d6));
            asm volatile("v_permlane32_swap_b32 %0, %1" : "+v"(d5), "+v"(d7));
            const half8 pa0 = (half8){ d0[0], d0[1], d1[0], d1[1],
                                       d2[0], d2[1], d3[0], d3[1] };  // kj-step 2*kt
            const half8 pa1 = (half8){ d4[0], d4[1], d5[0], d5[1],
                                       d6[0], d6[1], d7[0], d7[1] };  // kj-step 2*kt+1
            // PV: B-frag = V[kj][d] from KtS rows d; out col=d, row=q.
            {
                const int sg0 = 2 * kt;
                const half8 b00 = *(const half8*)&KtS[(0 * 32 + l31) * 64 +
                                                      (((2 * sg0 + hi) ^ (l31 & 7)) * 8)];
                const half8 b01 = *(const half8*)&KtS[(0 * 32 + l31) * 64 +
                                                      (((2 * sg0 + 2 + hi) ^ (l31 & 7)) * 8)];
                O0 = __builtin_amdgcn_mfma_f32_32x32x16_f16(pa0, b00, O0, 0, 0, 0);
                O0 = __builtin_amdgcn_mfma_f32_32x32x16_f16(pa1, b01, O0, 0, 0, 0);
                const half8 b10 = *(const half8*)&KtS[(1 * 32 + l31) * 64 +
                                                      (((2 * sg0 + hi) ^ (l31 & 7)) * 8)];
                const half8 b11 = *(const half8*)&KtS[(1 * 32 + l31) * 64 +
                                                      (((2 * sg0 + 2 + hi) ^ (l31 & 7)) * 8)];
                O1 = __builtin_amdgcn_mfma_f32_32x32x16_f16(pa0, b10, O1, 0, 0, 0);
                O1 = __builtin_amdgcn_mfma_f32_32x32x16_f16(pa1, b11, O1, 0, 0, 0);
            }
        }
    }

    // ---- epilogue: full row-sum, 1/l broadcast, coalesced fp32 stores ----
    const float lt = lsum + __shfl_xor(lsum, 32, 64);   // full sum for q = q0 + l31
    float* ob = out + (size_t)b * S_LEN * DM + h * DH;
    #pragma unroll
    for (int r = 0; r < 16; ++r) {
        const int qr = (r & 3) + 8 * (r >> 2) + 4 * hi;     // 0..31
        const float inv = 1.0f / __shfl(lt, qr, 64);        // lt lives at lane qr
        ob[(size_t)(q0 + qr) * DM + l31]      = O0[r] * inv;
        ob[(size_t)(q0 + qr) * DM + 32 + l31] = O1[r] * inv;
    }
}

extern "C" void kernel_launch(void* const* d_in, const int* in_sizes, int n_in,
                              void* d_out, int out_size, void* d_ws, size_t ws_size,
                              hipStream_t stream) {
    const float* Q = (const float*)d_in[0];   // K, V ignored per reference
    float* out = (float*)d_out;
    (void)d_ws; (void)ws_size;                 // fused kernel needs no workspace
    attn_v11_kernel<<<dim3(NBH * (S_LEN / 64)), dim3(128), 0, stream>>>(Q, out);
}

// Round 23
// 199.451 us; speedup vs baseline: 1.5615x; 1.5615x over previous
//
#include <hip/hip_runtime.h>
#include <stdint.h>

// B=4, S=2048, H=16, Dh=64, model dim 1024. K,V inputs ignored (reference
// attends Q against itself).
#define S_LEN 2048
#define DH    64
#define NH    16
#define DM    1024
#define NBH   64
#define NT    (S_LEN / 64)

typedef float    f32x16 __attribute__((ext_vector_type(16)));
typedef float    f32x4  __attribute__((ext_vector_type(4)));
typedef _Float16 half8  __attribute__((ext_vector_type(8)));
typedef _Float16 half4  __attribute__((ext_vector_type(4)));
typedef _Float16 half2v __attribute__((ext_vector_type(2)));

// ---------- attention v12: v10 compute, 8-wave WG to amortize staging ----------
// R22 post-mortem: v11 (2-wave WGs, 2x staging events) = 244us vs v10 115.3 --
// time ~ 2.1x with MFMA work constant and Occ UP (37->42.8). Accidental A/B
// proves STAGING dominates runtime (not barriers/occupancy/frag conflicts).
// v12 goes the other way: WG = 8 waves / 512 thr / 256 q; grid 512 WGs (8/bh).
// Staging events halve vs v10 (quarter vs v11); per-thread staging shrinks to
// {2 float4 + 1 ds_write_b128} (A) + {4 float2 + 2 half4} (B). Pass-A writes
// are bank-uniform: per row the 8 chunks (c8^(rA&7)) cover all 32 banks.
// Compute per wave: v10 verbatim (32x32 MFMA, P in regs via cvt_pkrtz +
// v_permlane32_swap_b32; layout HW-validated R19). LDS 16KB/WG -> 2 WGs/CU
// = 16 waves. No launch_bounds (v7/v9 spill lesson).
// LDS element (row,c) at row*64 + ((c>>3) ^ (row&7))*8 + (c&7).
// XCD swizzle: 512 WGs, %8==0 -> bijective logical=(bid&7)*64+(bid>>3).
__global__ void attn_v12_kernel(const float* __restrict__ Q,
                                float* __restrict__ out) {
    __shared__ __align__(16) _Float16 KnS[64 * 64];      // [kj][d]  8 KB
    __shared__ __align__(16) _Float16 KtS[64 * 64];      // [d][kj]  8 KB

    const int tid  = threadIdx.x;
    const int w    = tid >> 6;             // 0..7
    const int lane = tid & 63;
    const int l31  = lane & 31;
    const int hi   = lane >> 5;

    const int bid     = blockIdx.x;
    const int logical = (bid & 7) * 64 + (bid >> 3);    // bijective: 512 % 8 == 0
    const int qblk    = logical & 7;       // 8 WGs per bh (256 q each)
    const int bh      = logical >> 3;
    const int b = bh >> 4, h = bh & 15;
    const int q0      = qblk * 256 + w * 32;  // 32 q per wave

    const float* qbase = Q + (size_t)b * S_LEN * DM + h * DH;   // + s*DM + d

    // Q fragments (B-operand of S^T): lane holds Q[q=q0+l31][d = s*16 + hi*8 + j]
    half8 qreg[4];
    #pragma unroll
    for (int s = 0; s < 4; ++s) {
        const float* p = qbase + (size_t)(q0 + l31) * DM + s * 16 + hi * 8;
        const float4 f0 = *(const float4*)p;
        const float4 f1 = *(const float4*)(p + 4);
        qreg[s] = (half8){ (_Float16)f0.x, (_Float16)f0.y, (_Float16)f0.z, (_Float16)f0.w,
                           (_Float16)f1.x, (_Float16)f1.y, (_Float16)f1.z, (_Float16)f1.w };
    }

    // fixed per-row m = qs*||q||^2 (validated R1/R2). lane's d-subset + partner's.
    const float qs = 0.18033688011112042f;   // log2(e)/sqrt(64)
    float part = 0.f;
    #pragma unroll
    for (int s = 0; s < 4; ++s)
        #pragma unroll
        for (int j = 0; j < 8; ++j) { const float x = (float)qreg[s][j]; part += x * x; }
    part += __shfl_xor(part, 32, 64);
    const float m_c = qs * part;             // for row q = q0 + l31

    // ---- staging pass A (KnS): rA = tid>>3 (row), c8 = tid&7 (8-col chunk) ----
    // 8 lanes cover one row (64 floats); write = one swizzled half8 (b128).
    const int rA = tid >> 3;               // 0..63
    const int c8 = tid & 7;                // 0..7
    const float* srcA = qbase + (size_t)rA * DM + c8 * 8;        // + tt*64*DM
    _Float16* knA = &KnS[rA * 64 + ((c8 ^ (rA & 7)) * 8)];
    // ---- staging pass B (KtS): kj0=(tid&15)*4, d0b=(tid>>4)*2 (2 d-rows) ----
    const int kj0 = (tid & 15) * 4;        // 0..60
    const int d0b = (tid >> 4) * 2;        // 0..62
    const float* srcB = qbase + (size_t)kj0 * DM + d0b;          // + tt*64*DM + i*DM
    _Float16* ktB[2];
    #pragma unroll
    for (int dd = 0; dd < 2; ++dd) {
        const int dr = d0b + dd;
        ktB[dd] = &KtS[dr * 64 + (((kj0 >> 3) ^ (dr & 7)) * 8) + (kj0 & 7)];
    }

    f32x16 O0 = { 0.f,0.f,0.f,0.f, 0.f,0.f,0.f,0.f, 0.f,0.f,0.f,0.f, 0.f,0.f,0.f,0.f };
    f32x16 O1 = { 0.f,0.f,0.f,0.f, 0.f,0.f,0.f,0.f, 0.f,0.f,0.f,0.f, 0.f,0.f,0.f,0.f };
    float lsum = 0.f;

    for (int tt = 0; tt < NT; ++tt) {
        __syncthreads();                         // prior tile's LDS reads done

        // ---- fused staging: fp32 tile -> f16 KnS + KtS ----
        const float4 a0 = *(const float4*)(srcA + (size_t)(tt * 64) * DM);
        const float4 a1 = *(const float4*)(srcA + (size_t)(tt * 64) * DM + 4);
        float2 bv[4];
        #pragma unroll
        for (int i = 0; i < 4; ++i)
            bv[i] = *(const float2*)(srcB + (size_t)(tt * 64 + i) * DM);

        const half8 ha = (half8){ (_Float16)a0.x, (_Float16)a0.y, (_Float16)a0.z, (_Float16)a0.w,
                                  (_Float16)a1.x, (_Float16)a1.y, (_Float16)a1.z, (_Float16)a1.w };
        *(half8*)knA = ha;                       // row rA, d = c8*8 .. +7 (b128)
        #pragma unroll
        for (int dd = 0; dd < 2; ++dd) {
            const half4 tv = (half4){ (_Float16)bv[0][dd], (_Float16)bv[1][dd],
                                      (_Float16)bv[2][dd], (_Float16)bv[3][dd] };
            *(half4*)ktB[dd] = tv;               // row d0b+dd, kj = kj0..kj0+3
        }
        __syncthreads();                         // tile visible to all waves

        // ---- per kj-tile (kt): S^T (4 chained MFMAs) -> exp -> pack/swap -> PV ----
        #pragma unroll
        for (int kt = 0; kt < 2; ++kt) {
            f32x16 acc = { 0.f,0.f,0.f,0.f, 0.f,0.f,0.f,0.f,
                           0.f,0.f,0.f,0.f, 0.f,0.f,0.f,0.f };
            #pragma unroll
            for (int s = 0; s < 4; ++s) {
                const half8 a = *(const half8*)&KnS[(kt * 32 + l31) * 64 +
                                                    (((2 * s + hi) ^ (l31 & 7)) * 8)];
                acc = __builtin_amdgcn_mfma_f32_32x32x16_f16(a, qreg[s], acc, 0, 0, 0);
            }
            // p[r] = exp2(qs*S - m) for kj=(r&3)+8*(r>>2)+4*hi+32*kt, q=l31
            float p[16];
            #pragma unroll
            for (int r = 0; r < 16; ++r) {
                p[r] = __builtin_amdgcn_exp2f(__builtin_fmaf(acc[r], qs, -m_c));
                lsum += p[r];
            }
            // pack pairs -> dwords (kj ascending within each 4-block)
            half2v d0 = __builtin_bit_cast(half2v, __builtin_amdgcn_cvt_pkrtz(p[0],  p[1]));   // kj 0,1 (+4hi)
            half2v d1 = __builtin_bit_cast(half2v, __builtin_amdgcn_cvt_pkrtz(p[2],  p[3]));   // kj 2,3
            half2v d2 = __builtin_bit_cast(half2v, __builtin_amdgcn_cvt_pkrtz(p[4],  p[5]));   // kj 8,9
            half2v d3 = __builtin_bit_cast(half2v, __builtin_amdgcn_cvt_pkrtz(p[6],  p[7]));   // kj 10,11
            half2v d4 = __builtin_bit_cast(half2v, __builtin_amdgcn_cvt_pkrtz(p[8],  p[9]));   // kj 16,17
            half2v d5 = __builtin_bit_cast(half2v, __builtin_amdgcn_cvt_pkrtz(p[10], p[11]));  // kj 18,19
            half2v d6 = __builtin_bit_cast(half2v, __builtin_amdgcn_cvt_pkrtz(p[12], p[13]));  // kj 24,25
            half2v d7 = __builtin_bit_cast(half2v, __builtin_amdgcn_cvt_pkrtz(p[14], p[15]));  // kj 26,27
            // half-exchange: v_permlane32_swap: a.hi32lanes <-> b.lo32lanes.
            asm volatile("v_permlane32_swap_b32 %0, %1" : "+v"(d0), "+v"(d2));
            asm volatile("v_permlane32_swap_b32 %0, %1" : "+v"(d1), "+v"(d3));
            asm volatile("v_permlane32_swap_b32 %0, %1" : "+v"(d4), "+v"(d6));
            asm volatile("v_permlane32_swap_b32 %0, %1" : "+v"(d5), "+v"(d7));
            const half8 pa0 = (half8){ d0[0], d0[1], d1[0], d1[1],
                                       d2[0], d2[1], d3[0], d3[1] };  // kj-step 2*kt
            const half8 pa1 = (half8){ d4[0], d4[1], d5[0], d5[1],
                                       d6[0], d6[1], d7[0], d7[1] };  // kj-step 2*kt+1
            // PV: B-frag = V[kj][d] from KtS rows d; out col=d, row=q.
            {
                const int sg0 = 2 * kt;
                const half8 b00 = *(const half8*)&KtS[(0 * 32 + l31) * 64 +
                                                      (((2 * sg0 + hi) ^ (l31 & 7)) * 8)];
                const half8 b01 = *(const half8*)&KtS[(0 * 32 + l31) * 64 +
                                                      (((2 * sg0 + 2 + hi) ^ (l31 & 7)) * 8)];
                O0 = __builtin_amdgcn_mfma_f32_32x32x16_f16(pa0, b00, O0, 0, 0, 0);
                O0 = __builtin_amdgcn_mfma_f32_32x32x16_f16(pa1, b01, O0, 0, 0, 0);
                const half8 b10 = *(const half8*)&KtS[(1 * 32 + l31) * 64 +
                                                      (((2 * sg0 + hi) ^ (l31 & 7)) * 8)];
                const half8 b11 = *(const half8*)&KtS[(1 * 32 + l31) * 64 +
                                                      (((2 * sg0 + 2 + hi) ^ (l31 & 7)) * 8)];
                O1 = __builtin_amdgcn_mfma_f32_32x32x16_f16(pa0, b10, O1, 0, 0, 0);
                O1 = __builtin_amdgcn_mfma_f32_32x32x16_f16(pa1, b11, O1, 0, 0, 0);
            }
        }
    }

    // ---- epilogue: full row-sum, 1/l broadcast, coalesced fp32 stores ----
    const float lt = lsum + __shfl_xor(lsum, 32, 64);   // full sum for q = q0 + l31
    float* ob = out + (size_t)b * S_LEN * DM + h * DH;
    #pragma unroll
    for (int r = 0; r < 16; ++r) {
        const int qr = (r & 3) + 8 * (r >> 2) + 4 * hi;     // 0..31
        const float inv = 1.0f / __shfl(lt, qr, 64);        // lt lives at lane qr
        ob[(size_t)(q0 + qr) * DM + l31]      = O0[r] * inv;
        ob[(size_t)(q0 + qr) * DM + 32 + l31] = O1[r] * inv;
    }
}

extern "C" void kernel_launch(void* const* d_in, const int* in_sizes, int n_in,
                              void* d_out, int out_size, void* d_ws, size_t ws_size,
                              hipStream_t stream) {
    const float* Q = (const float*)d_in[0];   // K, V ignored per reference
    float* out = (float*)d_out;
    (void)d_ws; (void)ws_size;                 // fused kernel needs no workspace
    attn_v12_kernel<<<dim3(NBH * (S_LEN / 256)), dim3(512), 0, stream>>>(Q, out);
}